// Round 10
// baseline (169.022 us; speedup 1.0000x reference)
//
#include <hip/hip_runtime.h>
#include <math.h>

// CapsuleLayer dynamic routing, fused. R10: LDS-staged W, MB=2, bsel in-wave.
// Ledger: 64-VGPR cap is immovable (R2/R3/R6/R7/R9); R8 (pri[9]=36 regs,
// VGPR 40) is the clean shape. R8's 88 us is address-divergence-bound:
// each W wave-load = 16 disjoint 64-B segments (~16 TA-cyc/inst, ~48 us/CU).
// Fix: stage W tiles (128 rows, 64 KB, +1-float4 row pad) into LDS with
// fully-coalesced loads, consume strided from LDS. Two batches per block
// share the tile; bsel lives INSIDE the wave (lane = bsel*32 + rl*4 + og)
// so bsel-pairs ds_read identical addresses -> LDS broadcast (free).
// Per-thread regs stay at R8 level (one batch per thread, pri[9]).
// W traffic: 1280 blocks x 589 KB = 755 MB coalesced (~22 us L2).
// LDS 69.9 KB -> 2 blocks/CU x 1024 thr = 32 waves = 100% occupancy.
// Logits overlay the dead W-tile region in Phase B.

#define NC 10
#define NR 1152
#define IC 8
#define OC 16
#define NITER 3
#define T 1024
#define WROW 33            // padded row stride, float4 units (32 data + 1 pad)

__global__ __launch_bounds__(T) void caps_route(
    const float* __restrict__ x,   // [B, NR, IC]
    const float* __restrict__ W,   // [NC, NR, IC, OC]
    float* __restrict__ out)       // [B, NC, OC]
{
    __shared__ float4 wtile[128 * WROW];   // 67584 B; Phase B: logit[2][NR] overlay
    __shared__ float redm[2 * 16];         // per-batch per-wave stats
    __shared__ float sred[2 * 16 * 16];    // per-batch per-wave s[o] partials
    __shared__ float vout[2 * OC];

    const int t    = threadIdx.x;
    const int lane = t & 63;
    const int wid  = t >> 6;               // 0..15
    const int og   = lane & 3;             // o-quad
    const int rl   = (lane >> 2) & 7;      // row-local within wave
    const int bsel = lane >> 5;            // batch select, inside the wave
    const int rr   = wid * 8 + rl;         // 0..127: owned row class
    const int th   = wid * 32 + (lane & 31); // 0..511 index within own batch

    const int c  = blockIdx.x >> 7;        // c-major: 128 consecutive blocks share W[c]
    const int b0 = (blockIdx.x & 127) * 2;

    const float4* __restrict__ wb = (const float4*)(W + (size_t)c * (NR * IC * OC));
    const float4* __restrict__ xb = (const float4*)(x + (size_t)(b0 + bsel) * (NR * IC));

    // ---------------- Phase A: 9 tiles of 128 rows --------------------------
    float4 pri[9];
#pragma unroll
    for (int p = 0; p < 9; ++p) {
        const float4* wt = wb + p * 4096;  // tile p: rows 128p..128p+127
        if (p) __syncthreads();            // previous tile fully consumed
#pragma unroll
        for (int q = 0; q < 4; ++q) {      // coalesced stage: 1 KB/wave-inst
            const int g = t + (q << 10);   // float4 idx in tile, 0..4095
            wtile[(g >> 5) * WROW + (g & 31)] = wt[g];
        }
        __syncthreads();

        const int r = rr + (p << 7);       // this thread's row in tile p
        const float4* wrow = wtile + rr * WROW + og;
        float4 acc = make_float4(0.f, 0.f, 0.f, 0.f);
        float4 xa = xb[2 * r];
        {
            float xs[4] = {xa.x, xa.y, xa.z, xa.w};
#pragma unroll
            for (int i = 0; i < 4; ++i) {
                float4 w = wrow[i * 4];
                acc.x = fmaf(xs[i], w.x, acc.x);
                acc.y = fmaf(xs[i], w.y, acc.y);
                acc.z = fmaf(xs[i], w.z, acc.z);
                acc.w = fmaf(xs[i], w.w, acc.w);
            }
        }
        float4 xc = xb[2 * r + 1];
        {
            float xs[4] = {xc.x, xc.y, xc.z, xc.w};
#pragma unroll
            for (int i = 0; i < 4; ++i) {
                float4 w = wrow[(i + 4) * 4];
                acc.x = fmaf(xs[i], w.x, acc.x);
                acc.y = fmaf(xs[i], w.y, acc.y);
                acc.z = fmaf(xs[i], w.z, acc.z);
                acc.w = fmaf(xs[i], w.w, acc.w);
            }
        }
        pri[p] = acc;
    }

    float* logits = (float*)wtile;         // overlay: W dead after Phase A
    float* lg = logits + bsel * NR;        // own batch's collapsed logits

    // ---------------- Phase B: 3 routing iterations -------------------------
    for (int it = 0; it < NITER; ++it) {
        const bool uni = (it == 0);        // softmax of zeros = uniform
        float m = 0.f, invd = 0.f;
        if (!uni) {
            float lm = -3.4e38f;
#pragma unroll
            for (int k = 0; k < 3; ++k) {
                int r = th + (k << 9);
                if (r < NR) lm = fmaxf(lm, lg[r]);
            }
#pragma unroll
            for (int msk = 1; msk <= 16; msk <<= 1)   // reduce within 32-lane half
                lm = fmaxf(lm, __shfl_xor(lm, msk, 64));
            if ((lane & 31) == 0) redm[bsel * 16 + wid] = lm;
            __syncthreads();
            m = redm[bsel * 16];
#pragma unroll
            for (int w = 1; w < 16; ++w) m = fmaxf(m, redm[bsel * 16 + w]);
            float e = 0.f;
#pragma unroll
            for (int k = 0; k < 3; ++k) {
                int r = th + (k << 9);
                if (r < NR) e += __expf(lg[r] - m);
            }
#pragma unroll
            for (int msk = 1; msk <= 16; msk <<= 1)
                e += __shfl_xor(e, msk, 64);
            __syncthreads();               // m reads done before redm rewrite
            if ((lane & 31) == 0) redm[bsel * 16 + wid] = e;
            __syncthreads();
            float den = redm[bsel * 16];
#pragma unroll
            for (int w = 1; w < 16; ++w) den += redm[bsel * 16 + w];
            invd = 1.f / den;
        }

        // s[o] partial over owned rows
        float4 s4 = make_float4(0.f, 0.f, 0.f, 0.f);
#pragma unroll
        for (int p = 0; p < 9; ++p) {
            float wgt = 1.0f;
            if (!uni) wgt = __expf(lg[rr + (p << 7)] - m);
            s4.x = fmaf(wgt, pri[p].x, s4.x);
            s4.y = fmaf(wgt, pri[p].y, s4.y);
            s4.z = fmaf(wgt, pri[p].z, s4.z);
            s4.w = fmaf(wgt, pri[p].w, s4.w);
        }
        // reduce over the 8 rl slots (same og,bsel) within the wave
#pragma unroll
        for (int msk = 4; msk <= 16; msk <<= 1) {
            s4.x += __shfl_xor(s4.x, msk, 64);
            s4.y += __shfl_xor(s4.y, msk, 64);
            s4.z += __shfl_xor(s4.z, msk, 64);
            s4.w += __shfl_xor(s4.w, msk, 64);
        }
        __syncthreads();                   // prior sred/redm reads & tile reads done
        if ((lane & 31) < 4)               // og lanes of each half
            ((float4*)sred)[(bsel * 16 + wid) * 4 + og] = s4;
        __syncthreads();

        if (t < 2 * OC) {                  // lanes 0..31 of wave 0
            const int bs = t >> 4, o = t & 15;
            float s = 0.f;
#pragma unroll
            for (int w = 0; w < 16; ++w) s += sred[(bs * 16 + w) * 16 + o];
            float scl;
            if (uni) {
                scl = 1.0f / 1152.0f;
            } else {
                float den = redm[bs * 16];   // recompute for OWN bs (lane bsel==0 here)
#pragma unroll
                for (int w = 1; w < 16; ++w) den += redm[bs * 16 + w];
                scl = 1.f / den;
            }
            s *= scl;
            float sq = s * s;
#pragma unroll
            for (int msk = 1; msk <= 8; msk <<= 1) sq += __shfl_xor(sq, msk, 64);
            float v = s * (sqrtf(sq) / (1.0f + sq));   // squash
            if (it == NITER - 1) out[((size_t)(b0 + bs) * NC + c) * OC + o] = v;
            else vout[t] = v;
        }
        __syncthreads();

        if (it < NITER - 1) {
            // logit[r] += sum_o pri[r][o]*v[o]
            float4 v4 = ((const float4*)(vout + bsel * OC))[og];
#pragma unroll
            for (int p = 0; p < 9; ++p) {
                const int r = rr + (p << 7);
                float d = pri[p].x * v4.x + pri[p].y * v4.y +
                          pri[p].z * v4.z + pri[p].w * v4.w;
                d += __shfl_xor(d, 1, 64);
                d += __shfl_xor(d, 2, 64);
                if (og == 0) {
                    if (it == 0) lg[r] = d;    // logits start at zero
                    else         lg[r] += d;
                }
            }
            __syncthreads();
        }
    }
}

extern "C" void kernel_launch(void* const* d_in, const int* in_sizes, int n_in,
                              void* d_out, int out_size, void* d_ws, size_t ws_size,
                              hipStream_t stream) {
    const float* x = (const float*)d_in[0];
    const float* W = (const float*)d_in[1];
    float* out = (float*)d_out;
    caps_route<<<dim3(NC * 128), dim3(T), 0, stream>>>(x, W, out);
}